// Round 17
// baseline (175.776 us; speedup 1.0000x reference)
//
#include <hip/hip_runtime.h>

typedef _Float16 h8 __attribute__((ext_vector_type(8)));
typedef _Float16 h4 __attribute__((ext_vector_type(4)));
typedef _Float16 h2 __attribute__((ext_vector_type(2)));
typedef float f4 __attribute__((ext_vector_type(4)));
typedef float f16x16 __attribute__((ext_vector_type(16)));

#define LOG2E 1.44269504088896340736f

#define BARRIER_ACQ do { __builtin_amdgcn_s_barrier(); \
                         asm volatile("" ::: "memory"); } while (0)
#define BARRIER_REL do { asm volatile("" ::: "memory"); \
                         __builtin_amdgcn_s_barrier(); } while (0)

__device__ __forceinline__ void gload_lds16(const void* g, void* l) {
    __builtin_amdgcn_global_load_lds(
        (const __attribute__((address_space(1))) void*)g,
        (__attribute__((address_space(3))) void*)l, 16, 0, 0);
}

// ---------------------------------------------------------------------------
// Kernel 1: batched f32 -> f16 cast
// ---------------------------------------------------------------------------
struct CastArgs { const float* src[10]; _Float16* dst[10]; };

__global__ __launch_bounds__(256) void cast_all_kernel(CastArgs a) {
    int blk = blockIdx.x;
    int seg, rel;
    if (blk < 4096)      { seg = 0; rel = blk; }
    else if (blk < 4608) { seg = 1; rel = blk - 4096; }
    else { int t = blk - 4608; seg = 2 + (t >> 10); rel = t & 1023; }
    long base = ((long)rel * 256 + threadIdx.x) * 4;
    float4 v = *(const float4*)(a.src[seg] + base);
    h4 o = { (_Float16)v.x, (_Float16)v.y, (_Float16)v.z, (_Float16)v.w };
    *(h4*)(a.dst[seg] + base) = o;
}

// ---------------------------------------------------------------------------
// Kernel 2: fp16 GEMM, two segments, XCD-rectangle swizzle, double-buffered
//   LDS, counted vmcnt. Template GN = N-tile size (128 or 64).
// ---------------------------------------------------------------------------
struct GemmDesc {
    const _Float16* A[2];
    const _Float16* W[2];
    char*           C[2];
    const float*    bias[2][3];
    long bsA[2];
    long aoff[2];
    long bsC[2];
    int  mshift[2];
    int  mcut;
};

template<bool OUT_F32, int GN>
__global__ __launch_bounds__(256)
void gemm_kernel(GemmDesc g, int K, int N, int gm, int gn, int xgn)
{
    constexpr int NFRAG = GN / 32;
    __shared__ __align__(16) _Float16 As[2][128 * 64];
    __shared__ __align__(16) _Float16 Bs[2][GN * 64];
    const int lane = threadIdx.x & 63;
    const int wave = threadIdx.x >> 6;
    const int lid = blockIdx.x;
    const int xcd = lid & 7;
    const int r0 = lid >> 3;
    const int mtile = (xcd / xgn) * gm + (r0 % gm);
    const int ntile = (xcd % xgn) * gn + (r0 / gm);

    const int seg = mtile >= g.mcut;
    const int mloc = mtile - (seg ? g.mcut : 0);
    const int bidx = mloc >> g.mshift[seg];
    const int min_ = mloc & ((1 << g.mshift[seg]) - 1);
    const _Float16* Ab = g.A[seg] + (long)bidx * g.bsA[seg] + g.aoff[seg]
                         + (long)min_ * 128 * K;
    const _Float16* Bb = g.W[seg] + (long)ntile * GN * K;
    const long crow0 = (long)bidx * g.bsC[seg] + (long)min_ * 128 * N;

    const int wr = wave >> 1, wc = wave & 1;
    f4 acc[4][NFRAG] = {};

    auto stage = [&](int bf, int kt) {
#pragma unroll
        for (int it = 0; it < 4; ++it) {
            int r = wave * 32 + it * 8 + (lane >> 3);
            int lc = (lane & 7) ^ (r & 7);
            gload_lds16((const char*)(Ab + (long)r * K + kt) + lc * 16,
                        (char*)&As[bf][0] + (wave * 32 + it * 8) * 128);
        }
#pragma unroll
        for (int it = 0; it < GN / 32; ++it) {
            int r = wave * (GN / 4) + it * 8 + (lane >> 3);
            int lc = (lane & 7) ^ (r & 7);
            gload_lds16((const char*)(Bb + (long)r * K + kt) + lc * 16,
                        (char*)&Bs[bf][0] + (wave * (GN / 4) + it * 8) * 128);
        }
    };

    constexpr int NLOADS = 4 + GN / 32;
    const int nk = K >> 6;
    stage(0, 0);
    int buf = 0;
#pragma unroll 1
    for (int ki = 0; ki < nk; ++ki) {
        if (ki + 1 < nk) {
            stage(buf ^ 1, (ki + 1) << 6);
            if (NLOADS == 8)
                asm volatile("s_waitcnt vmcnt(8)" ::: "memory");
            else
                asm volatile("s_waitcnt vmcnt(6)" ::: "memory");
        } else {
            asm volatile("s_waitcnt vmcnt(0)" ::: "memory");
        }
        BARRIER_ACQ;
#pragma unroll
        for (int kk = 0; kk < 2; ++kk) {
            h8 af[4], bf4[NFRAG];
#pragma unroll
            for (int m = 0; m < 4; ++m) {
                int row = wr * 64 + m * 16 + (lane & 15);
                int pc = (kk * 4 + (lane >> 4)) ^ (row & 7);
                af[m] = *(const h8*)(&As[buf][row * 64 + pc * 8]);
            }
#pragma unroll
            for (int n = 0; n < NFRAG; ++n) {
                int row = wc * (GN / 2) + n * 16 + (lane & 15);
                int pc = (kk * 4 + (lane >> 4)) ^ (row & 7);
                bf4[n] = *(const h8*)(&Bs[buf][row * 64 + pc * 8]);
            }
#pragma unroll
            for (int m = 0; m < 4; ++m)
#pragma unroll
                for (int n = 0; n < NFRAG; ++n)
                    acc[m][n] = __builtin_amdgcn_mfma_f32_16x16x32_f16(
                        af[m], bf4[n], acc[m][n], 0, 0, 0);
        }
        BARRIER_REL;
        buf ^= 1;
    }

#pragma unroll
    for (int n = 0; n < NFRAG; ++n) {
        int col = ntile * GN + wc * (GN / 2) + n * 16 + (lane & 15);
        const float* bp = (col < 1024) ? g.bias[seg][0]
                        : (col < 2048) ? g.bias[seg][1] : g.bias[seg][2];
        float bv = bp[col & 1023];
#pragma unroll
        for (int m = 0; m < 4; ++m) {
            int lrow = wr * 64 + m * 16 + ((lane >> 4) << 2);
#pragma unroll
            for (int r = 0; r < 4; ++r) {
                float v = acc[m][n][r] + bv;
                long off = crow0 + (long)(lrow + r) * N + col;
                if (OUT_F32) ((float*)g.C[seg])[off] = v;
                else         ((_Float16*)g.C[seg])[off] = (_Float16)v;
            }
        }
    }
}

// ---------------------------------------------------------------------------
// Kernel 3: FUSED pass2 (RMSNorm+RoPE Q/K, blocks 0..1151) + V-transpose
//   (blocks 1152..1727).
// ---------------------------------------------------------------------------
__device__ __forceinline__ float ssum8(h8 v) {
    float s = 0.f;
#pragma unroll
    for (int j = 0; j < 8; ++j) { float f = (float)v[j]; s += f * f; }
    return s;
}
__device__ __forceinline__ float red8(float s) {
    s += __shfl_xor(s, 1); s += __shfl_xor(s, 2); s += __shfl_xor(s, 4);
    return s;
}
__device__ __forceinline__ h8 norm_rope(h8 v, float rs_, const float* g, float gmul,
                                        const float* cs, const float* sn, int vis) {
    float f[8];
#pragma unroll
    for (int j = 0; j < 8; ++j) f[j] = (float)v[j] * rs_ * g[j] * gmul;
    h8 o;
    if (vis) {
#pragma unroll
        for (int j = 0; j < 8; j += 2) {
            float a = f[j], b = f[j + 1];
            o[j]     = (_Float16)(a * cs[j]     - b * sn[j]);
            o[j + 1] = (_Float16)(b * cs[j + 1] + a * sn[j + 1]);
        }
    } else {
#pragma unroll
        for (int j = 0; j < 8; ++j) o[j] = (_Float16)f[j];
    }
    return o;
}

__global__ __launch_bounds__(256)
void pass2_kernel(const _Float16* __restrict__ Yv, const _Float16* __restrict__ Yt,
                  const float* __restrict__ gqv, const float* __restrict__ gkv_,
                  const float* __restrict__ gqt, const float* __restrict__ gkt,
                  const float* __restrict__ rc, const float* __restrict__ rs,
                  _Float16* __restrict__ Q, _Float16* __restrict__ Kd,
                  _Float16* __restrict__ Vt)
{
    __shared__ _Float16 T[64 * 136];
    if (blockIdx.x >= 1152) {
        const int blk = blockIdx.x - 1152;   // bh*18 + ntile
        const int bh = blk / 18, ntl = blk - bh * 18;
        const int b = bh >> 4, h = bh & 15;
        const int npos0 = ntl * 128;
        const _Float16* Y; long m0;
        if (ntl >= 2) { Y = Yv; m0 = (long)b * 2048 + (npos0 - 256); }
        else          { Y = Yt; m0 = (long)b * 256 + npos0; }
        const int t = threadIdx.x;
        const _Float16* src = Y + m0 * 3072 + 2048 + h * 64;
#pragma unroll
        for (int ri = 0; ri < 4; ++ri) {
            int row = ri * 32 + (t >> 3);
            int c8 = t & 7;
            h8 v = *(const h8*)(src + (long)row * 3072 + c8 * 8);
#pragma unroll
            for (int j = 0; j < 8; ++j)
                T[(c8 * 8 + j) * 136 + row] = v[j];
        }
        __syncthreads();
        const int d = t >> 2, ch = t & 3;
        _Float16* dst = Vt + ((long)bh * 64 + d) * 2304 + npos0 + ch * 32;
#pragma unroll
        for (int k = 0; k < 4; ++k)
            *(h8*)(dst + k * 8) = *(const h8*)(&T[d * 136 + ch * 32 + k * 8]);
        return;
    }
    const int wave = threadIdx.x >> 6;
    const int lane = threadIdx.x & 63;
    const int row = blockIdx.x * 4 + wave;
    const int is_vis = row < 4096;
    const _Float16* y;
    const float *gq, *gk;
    int b, n, npos;
    if (is_vis) {
        y = Yv + (long)row * 3072; gq = gqv; gk = gkv_;
        b = row >> 11; n = row & 2047; npos = 256 + n;
    } else {
        int r2 = row - 4096;
        y = Yt + (long)r2 * 3072; gq = gqt; gk = gkt;
        b = r2 >> 8; n = r2 & 255; npos = n;
    }
    const int h0 = lane >> 3;
    const int d0 = (lane & 7) * 8;

    h8 q0 = *(const h8*)(y + lane * 8);
    h8 q1 = *(const h8*)(y + 512 + lane * 8);
    h8 k0 = *(const h8*)(y + 1024 + lane * 8);
    h8 k1 = *(const h8*)(y + 1536 + lane * 8);

    float ga[8], gb[8];
    *(float4*)(ga)     = *(const float4*)(gq + d0);
    *(float4*)(ga + 4) = *(const float4*)(gq + d0 + 4);
    *(float4*)(gb)     = *(const float4*)(gk + d0);
    *(float4*)(gb + 4) = *(const float4*)(gk + d0 + 4);
    float cs[8], sn[8];
    if (is_vis) {
        *(float4*)(cs)     = *(const float4*)(rc + n * 64 + d0);
        *(float4*)(cs + 4) = *(const float4*)(rc + n * 64 + d0 + 4);
        *(float4*)(sn)     = *(const float4*)(rs + n * 64 + d0);
        *(float4*)(sn + 4) = *(const float4*)(rs + n * 64 + d0 + 4);
    }

    const float rq0 = rsqrtf(red8(ssum8(q0)) * (1.0f / 64.0f) + 1e-6f);
    const float rq1 = rsqrtf(red8(ssum8(q1)) * (1.0f / 64.0f) + 1e-6f);
    const float rk0 = rsqrtf(red8(ssum8(k0)) * (1.0f / 64.0f) + 1e-6f);
    const float rk1 = rsqrtf(red8(ssum8(k1)) * (1.0f / 64.0f) + 1e-6f);

    const float qmul = 0.125f * LOG2E;
    const long obA = (((long)b * 16 + h0)      * 2304 + npos) * 64 + d0;
    const long obB = (((long)b * 16 + h0 + 8)  * 2304 + npos) * 64 + d0;
    *(h8*)(Q + obA)  = norm_rope(q0, rq0, ga, qmul, cs, sn, is_vis);
    *(h8*)(Q + obB)  = norm_rope(q1, rq1, ga, qmul, cs, sn, is_vis);
    *(h8*)(Kd + obA) = norm_rope(k0, rk0, gb, 1.0f, cs, sn, is_vis);
    *(h8*)(Kd + obB) = norm_rope(k1, rk1, gb, 1.0f, cs, sn, is_vis);
}

// ---------------------------------------------------------------------------
// Kernel 4: flash attention — R13-proven body (256 thr, QBLK=128, KVBLK=64
//   double-buffered, stage->vmcnt(4)->barrier->compute->barrier, split psum).
//   Split-K ns in {2,4,6}: split = id/576 (576 blocks per split), nt=36/ns.
// ---------------------------------------------------------------------------
__device__ __forceinline__ void attn_stage(const char* Kt, const char* Vt, char* S,
                                           int bufB, int t,
                                           int gK0, int gK1, int gV0, int gV1,
                                           int ldsW) {
    const char* kt = Kt + (long)t * 8192;
    const char* vt = Vt + (long)t * 128;
    gload_lds16(kt + gK0, S + bufB + ldsW);
    gload_lds16(kt + gK1, S + bufB + 4096 + ldsW);
    gload_lds16(vt + gV0, S + 16384 + bufB + ldsW);
    gload_lds16(vt + gV1, S + 16384 + bufB + 4096 + ldsW);
}

__device__ __forceinline__ void pv_half(const float* p, const char* S, int vbase,
                                        const int* off, int kblk,
                                        f16x16* oacc, float& psum) {
    const h2 one2 = {(_Float16)1.f, (_Float16)1.f};
    float a0 = 0.f, a1 = 0.f;
#pragma unroll
    for (int kb = 0; kb < 2; ++kb) {
        unsigned w0 = __builtin_bit_cast(unsigned,
            __builtin_amdgcn_cvt_pkrtz(p[8 * kb + 0], p[8 * kb + 1]));
        unsigned w1 = __builtin_bit_cast(unsigned,
            __builtin_amdgcn_cvt_pkrtz(p[8 * kb + 2], p[8 * kb + 3]));
        unsigned w2 = __builtin_bit_cast(unsigned,
            __builtin_amdgcn_cvt_pkrtz(p[8 * kb + 4], p[8 * kb + 5]));
        unsigned w3 = __builtin_bit_cast(unsigned,
            __builtin_amdgcn_cvt_pkrtz(p[8 * kb + 6], p[8 * kb + 7]));
        a0 = __builtin_amdgcn_fdot2(__builtin_bit_cast(h2, w0), one2, a0, false);
        a1 = __builtin_amdgcn_fdot2(__builtin_bit_cast(h2, w1), one2, a1, false);
        a0 = __builtin_amdgcn_fdot2(__builtin_bit_cast(h2, w2), one2, a0, false);
        a1 = __builtin_amdgcn_fdot2(__builtin_bit_cast(h2, w3), one2, a1, false);
        asm("v_permlane32_swap_b32 %0, %1" : "+v"(w0), "+v"(w2));
        asm("v_permlane32_swap_b32 %0, %1" : "+v"(w1), "+v"(w3));
        union { unsigned u[4]; h8 v; } pa;
        pa.u[0] = w0; pa.u[1] = w1; pa.u[2] = w2; pa.u[3] = w3;
#pragma unroll
        for (int dblk = 0; dblk < 2; ++dblk) {
            h8 vb = *(const h8*)(S + vbase + dblk * 4096 + off[kblk * 2 + kb]);
            oacc[dblk] = __builtin_amdgcn_mfma_f32_32x32x16_f16(
                pa.v, vb, oacc[dblk], 0, 0, 0);
        }
    }
    psum += a0 + a1;
}

__device__ __forceinline__ void attn_tile(const char* S, int bufB, const int* off,
                                          const h8* qf, f16x16* oacc, float& psum) {
    const f16x16 kZero = {};
    f16x16 st0, st1;
    {
        h8 ka0 = *(const h8*)(S + bufB + off[0]);
        h8 ka1 = *(const h8*)(S + bufB + 4096 + off[0]);
        st0 = __builtin_amdgcn_mfma_f32_32x32x16_f16(ka0, qf[0], kZero, 0, 0, 0);
        st1 = __builtin_amdgcn_mfma_f32_32x32x16_f16(ka1, qf[0], kZero, 0, 0, 0);
    }
#pragma unroll
    for (int ds = 1; ds < 4; ++ds) {
        h8 ka0 = *(const h8*)(S + bufB + off[ds]);
        h8 ka1 = *(const h8*)(S + bufB + 4096 + off[ds]);
        st0 = __builtin_amdgcn_mfma_f32_32x32x16_f16(ka0, qf[ds], st0, 0, 0, 0);
        st1 = __builtin_amdgcn_mfma_f32_32x32x16_f16(ka1, qf[ds], st1, 0, 0, 0);
    }
    float p0[16], p1[16];
#pragma unroll
    for (int r = 0; r < 16; ++r) { p0[r] = exp2f(st0[r]); p1[r] = exp2f(st1[r]); }
    pv_half(p0, S, 16384 + bufB, off, 0, oacc, psum);
    pv_half(p1, S, 16384 + bufB, off, 1, oacc, psum);
}

__global__ __launch_bounds__(256, 4)
void attn_kernel(const _Float16* __restrict__ Qg,
                 const _Float16* __restrict__ Kg,
                 const _Float16* __restrict__ Vg,   // [bh][64][2304]
                 _Float16* __restrict__ Op,         // [ns][b][2304][1024]
                 float* __restrict__ Lp,            // [ns][bh][2304]
                 int nt, int cpx)
{
    __shared__ __align__(16) char S[32768];
    const int lane = threadIdx.x & 63;
    const int wave = threadIdx.x >> 6;
    const int l31 = lane & 31, hi = lane >> 5;
    const int d0 = blockIdx.x;
    const int id = (d0 & 7) * cpx + (d0 >> 3);
    const int split = id / 576;
    const int rem = id - split * 576;
    const int bh = rem / 18;
    const int qb = rem - bh * 18;
    const int b = bh >> 4, h = bh & 15;
    const _Float16* Qbh = Qg + (long)bh * 2304 * 64;
    const char* Kt = (const char*)(Kg + (long)bh * 2304 * 64) + (long)split * nt * 8192;
    const char* Vt = (const char*)(Vg + (long)bh * 64 * 2304) + (long)split * nt * 128;
    _Float16* Ops = Op + (long)split * 4718592;
    float* Lps = Lp + (long)split * 73728;
    const int q0 = qb * 128 + wave * 32;

    h8 qf[4];
#pragma unroll
    for (int ds = 0; ds < 4; ++ds)
        qf[ds] = *(const h8*)(Qbh + (long)(q0 + l31) * 64 + ds * 16 + hi * 8);

    const int sg16 = ((lane & 7) ^ (lane >> 3)) * 16;
    const int rK = wave * 8 + (lane >> 3);
    const int gK0 = rK * 128 + sg16;
    const int gK1 = gK0 + 32 * 128;
    const int gV0 = rK * 4608 + sg16;
    const int gV1 = gV0 + 32 * 4608;
    const int ldsW = wave * 1024;
    int off[4];
#pragma unroll
    for (int j = 0; j < 4; ++j)
        off[j] = l31 * 128 + (((j * 2 + hi) ^ (l31 & 7)) * 16);

    f16x16 oacc[2] = {};
    float psum = 0.f;

    attn_stage(Kt, Vt, S, 0, 0, gK0, gK1, gV0, gV1, ldsW);
    int buf = 0;
#pragma unroll 1
    for (int t = 0; t < nt; ++t) {
        if (t + 1 < nt) {
            attn_stage(Kt, Vt, S, (buf ^ 1) * 8192, t + 1, gK0, gK1, gV0, gV1, ldsW);
            asm volatile("s_waitcnt vmcnt(4)" ::: "memory");
        } else {
            asm volatile("s_waitcnt vmcnt(0)" ::: "memory");
        }
        BARRIER_ACQ;
        __builtin_amdgcn_s_setprio(1);
        attn_tile(S, buf * 8192, off, qf, oacc, psum);
        __builtin_amdgcn_s_setprio(0);
        BARRIER_REL;
        buf ^= 1;
    }

    float lsum = psum + __shfl_xor(psum, 32);
    if (hi == 0) Lps[(long)bh * 2304 + q0 + l31] = lsum;
#pragma unroll
    for (int dblk = 0; dblk < 2; ++dblk) {
        int dcol = h * 64 + dblk * 32 + l31;
#pragma unroll
        for (int r = 0; r < 16; ++r) {
            int qrow = q0 + (r & 3) + 8 * (r >> 2) + 4 * hi;
            Ops[((long)b * 2304 + qrow) * 1024 + dcol] = (_Float16)oacc[dblk][r];
        }
    }
}

// ---------------------------------------------------------------------------
// Kernel 5: combine ns KV-splits: O = sum(O_s) / sum(l_s).
// ---------------------------------------------------------------------------
__global__ __launch_bounds__(256)
void combine_kernel(const _Float16* __restrict__ Op,
                    const float* __restrict__ Lp,
                    _Float16* __restrict__ Oh, int ns)
{
    long i = ((long)blockIdx.x * 256 + threadIdx.x) * 8;
    long row = i >> 10;
    int bb = row >= 2304;
    int n = (int)row - bb * 2304;
    int h = ((int)i & 1023) >> 6;
    long lidx = ((long)(bb * 16 + h)) * 2304 + n;
    float l = 0.f;
    float acc[8] = {};
    for (int s = 0; s < ns; ++s) {
        l += Lp[(long)s * 73728 + lidx];
        h8 a = *(const h8*)(Op + (long)s * 4718592 + i);
#pragma unroll
        for (int j = 0; j < 8; ++j) acc[j] += (float)a[j];
    }
    float inv = 1.0f / l;
    h8 o;
#pragma unroll
    for (int j = 0; j < 8; ++j) o[j] = (_Float16)(acc[j] * inv);
    *(h8*)(Oh + i) = o;
}

// ---------------------------------------------------------------------------
extern "C" void kernel_launch(void* const* d_in, const int* in_sizes, int n_in,
                              void* d_out, int out_size, void* d_ws, size_t ws_size,
                              hipStream_t stream)
{
    const float* vis_x    = (const float*)d_in[0];
    const float* txt_x    = (const float*)d_in[1];
    const float* rope_cos = (const float*)d_in[2];
    const float* rope_sin = (const float*)d_in[3];
    const float* vis_qw = (const float*)d_in[4];
    const float* vis_qb = (const float*)d_in[5];
    const float* vis_kw = (const float*)d_in[6];
    const float* vis_kb = (const float*)d_in[7];
    const float* vis_vw = (const float*)d_in[8];
    const float* vis_vb = (const float*)d_in[9];
    const float* vis_ow = (const float*)d_in[10];
    const float* vis_ob = (const float*)d_in[11];
    const float* txt_qw = (const float*)d_in[12];
    const float* txt_qb = (const float*)d_in[13];
    const float* txt_kw = (const float*)d_in[14];
    const float* txt_kb = (const float*)d_in[15];
    const float* txt_vw = (const float*)d_in[16];
    const float* txt_vb = (const float*)d_in[17];
    const float* txt_ow = (const float*)d_in[18];
    const float* txt_ob = (const float*)d_in[19];
    const float* vis_qn = (const float*)d_in[20];
    const float* vis_kn = (const float*)d_in[21];
    const float* txt_qn = (const float*)d_in[22];
    const float* txt_kn = (const float*)d_in[23];

    char* ws = (char*)d_ws;
    _Float16* Xvis  = (_Float16*)(ws);
    _Float16* Xtxt  = (_Float16*)(ws + 8388608);
    _Float16* Qh    = (_Float16*)(ws);              // aliases X (dead after QKV gemm)
    _Float16* WqkvV = (_Float16*)(ws + 9437184);
    _Float16* WqkvT = (_Float16*)(ws + 15728640);
    _Float16* WoV   = (_Float16*)(ws + 22020096);
    _Float16* WoT   = (_Float16*)(ws + 24117248);
    _Float16* Yvis  = (_Float16*)(ws + 26214400);   // dead after pass2
    _Float16* Ytxt  = (_Float16*)(ws + 51380224);   // dead after pass2
    _Float16* Kh    = (_Float16*)(ws + 54525952);
    _Float16* Vth   = (_Float16*)(ws + 63963136);

    // split-K factor: 6 if workspace allows 6 partial slabs, else 4, else 2.
    int ns;
    if      (ws_size >= 131792896) ns = 6;
    else if (ws_size >= 112328704) ns = 4;
    else                           ns = 2;
    const int nt = 36 / ns;                         // KV tiles of 64 per split
    _Float16* OpP;
    if (ns >= 4) OpP = (_Float16*)(ws + 73400320);
    else         OpP = (_Float16*)(ws + 26214400);
    float* LpP = (float*)((char*)OpP + (size_t)ns * 9437184);
    _Float16* Oh = OpP;   // combine output aliases partial 0 (read-before-write)

    CastArgs ca;
    ca.src[0] = vis_x;  ca.dst[0] = Xvis;
    ca.src[1] = txt_x;  ca.dst[1] = Xtxt;
    ca.src[2] = vis_qw; ca.dst[2] = WqkvV;
    ca.src[3] = vis_kw; ca.dst[3] = WqkvV + 1048576;
    ca.src[4] = vis_vw; ca.dst[4] = WqkvV + 2097152;
    ca.src[5] = txt_qw; ca.dst[5] = WqkvT;
    ca.src[6] = txt_kw; ca.dst[6] = WqkvT + 1048576;
    ca.src[7] = txt_vw; ca.dst[7] = WqkvT + 2097152;
    ca.src[8] = vis_ow; ca.dst[8] = WoV;
    ca.src[9] = txt_ow; ca.dst[9] = WoT;
    cast_all_kernel<<<12800, 256, 0, stream>>>(ca);

    GemmDesc gq;
    gq.A[0] = Xvis;  gq.A[1] = Xtxt;
    gq.W[0] = WqkvV; gq.W[1] = WqkvT;
    gq.C[0] = (char*)Yvis; gq.C[1] = (char*)Ytxt;
    gq.bias[0][0] = vis_qb; gq.bias[0][1] = vis_kb; gq.bias[0][2] = vis_vb;
    gq.bias[1][0] = txt_qb; gq.bias[1][1] = txt_kb; gq.bias[1][2] = txt_vb;
    gq.bsA[0] = 0; gq.bsA[1] = 0;
    gq.aoff[0] = 0; gq.aoff[1] = 0;
    gq.bsC[0] = 0; gq.bsC[1] = 0;
    gq.mshift[0] = 5; gq.mshift[1] = 5;
    gq.mcut = 32;
    gemm_kernel<false, 128><<<864, 256, 0, stream>>>(gq, 1024, 3072, 9, 12, 2);

    pass2_kernel<<<1728, 256, 0, stream>>>(
        Yvis, Ytxt, vis_qn, vis_kn, txt_qn, txt_kn, rope_cos, rope_sin,
        Qh, Kh, Vth);

    attn_kernel<<<576 * ns, 256, 0, stream>>>(Qh, Kh, Vth, OpP, LpP, nt, 72 * ns);
    combine_kernel<<<2304, 256, 0, stream>>>(OpP, LpP, Oh, ns);

    GemmDesc go;
    go.A[0] = Oh; go.A[1] = Oh;
    go.W[0] = WoV; go.W[1] = WoT;
    go.C[0] = (char*)d_out; go.C[1] = (char*)((float*)d_out + 4194304);
    go.bias[0][0] = vis_ob; go.bias[0][1] = vis_ob; go.bias[0][2] = vis_ob;
    go.bias[1][0] = txt_ob; go.bias[1][1] = txt_ob; go.bias[1][2] = txt_ob;
    go.bsA[0] = 2359296;  go.bsA[1] = 2359296;
    go.aoff[0] = 262144;  go.aoff[1] = 0;
    go.bsC[0] = 2097152;  go.bsC[1] = 262144;
    go.mshift[0] = 4; go.mshift[1] = 1;
    go.mcut = 32;
    gemm_kernel<true, 64><<<576, 256, 0, stream>>>(go, 1024, 1024, 9, 8, 2);
}

// Round 18
// 168.048 us; speedup vs baseline: 1.0460x; 1.0460x over previous
//
#include <hip/hip_runtime.h>

typedef _Float16 h8 __attribute__((ext_vector_type(8)));
typedef _Float16 h4 __attribute__((ext_vector_type(4)));
typedef _Float16 h2 __attribute__((ext_vector_type(2)));
typedef float f4 __attribute__((ext_vector_type(4)));
typedef float f16x16 __attribute__((ext_vector_type(16)));

#define LOG2E 1.44269504088896340736f

#define BARRIER_ACQ do { __builtin_amdgcn_s_barrier(); \
                         asm volatile("" ::: "memory"); } while (0)
#define BARRIER_REL do { asm volatile("" ::: "memory"); \
                         __builtin_amdgcn_s_barrier(); } while (0)

__device__ __forceinline__ void gload_lds16(const void* g, void* l) {
    __builtin_amdgcn_global_load_lds(
        (const __attribute__((address_space(1))) void*)g,
        (__attribute__((address_space(3))) void*)l, 16, 0, 0);
}

// ---------------------------------------------------------------------------
// Kernel 1: batched f32 -> f16 cast
// ---------------------------------------------------------------------------
struct CastArgs { const float* src[10]; _Float16* dst[10]; };

__global__ __launch_bounds__(256) void cast_all_kernel(CastArgs a) {
    int blk = blockIdx.x;
    int seg, rel;
    if (blk < 4096)      { seg = 0; rel = blk; }
    else if (blk < 4608) { seg = 1; rel = blk - 4096; }
    else { int t = blk - 4608; seg = 2 + (t >> 10); rel = t & 1023; }
    long base = ((long)rel * 256 + threadIdx.x) * 4;
    float4 v = *(const float4*)(a.src[seg] + base);
    h4 o = { (_Float16)v.x, (_Float16)v.y, (_Float16)v.z, (_Float16)v.w };
    *(h4*)(a.dst[seg] + base) = o;
}

// ---------------------------------------------------------------------------
// Kernel 2: fp16 GEMM, two segments, XCD-rectangle swizzle, double-buffered
//   LDS, counted vmcnt. Template GN = N-tile size (128 or 64).
// ---------------------------------------------------------------------------
struct GemmDesc {
    const _Float16* A[2];
    const _Float16* W[2];
    char*           C[2];
    const float*    bias[2][3];
    long bsA[2];
    long aoff[2];
    long bsC[2];
    int  mshift[2];
    int  mcut;
};

template<bool OUT_F32, int GN>
__global__ __launch_bounds__(256)
void gemm_kernel(GemmDesc g, int K, int N, int gm, int gn, int xgn)
{
    constexpr int NFRAG = GN / 32;
    __shared__ __align__(16) _Float16 As[2][128 * 64];
    __shared__ __align__(16) _Float16 Bs[2][GN * 64];
    const int lane = threadIdx.x & 63;
    const int wave = threadIdx.x >> 6;
    const int lid = blockIdx.x;
    const int xcd = lid & 7;
    const int r0 = lid >> 3;
    const int mtile = (xcd / xgn) * gm + (r0 % gm);
    const int ntile = (xcd % xgn) * gn + (r0 / gm);

    const int seg = mtile >= g.mcut;
    const int mloc = mtile - (seg ? g.mcut : 0);
    const int bidx = mloc >> g.mshift[seg];
    const int min_ = mloc & ((1 << g.mshift[seg]) - 1);
    const _Float16* Ab = g.A[seg] + (long)bidx * g.bsA[seg] + g.aoff[seg]
                         + (long)min_ * 128 * K;
    const _Float16* Bb = g.W[seg] + (long)ntile * GN * K;
    const long crow0 = (long)bidx * g.bsC[seg] + (long)min_ * 128 * N;

    const int wr = wave >> 1, wc = wave & 1;
    f4 acc[4][NFRAG] = {};

    auto stage = [&](int bf, int kt) {
#pragma unroll
        for (int it = 0; it < 4; ++it) {
            int r = wave * 32 + it * 8 + (lane >> 3);
            int lc = (lane & 7) ^ (r & 7);
            gload_lds16((const char*)(Ab + (long)r * K + kt) + lc * 16,
                        (char*)&As[bf][0] + (wave * 32 + it * 8) * 128);
        }
#pragma unroll
        for (int it = 0; it < GN / 32; ++it) {
            int r = wave * (GN / 4) + it * 8 + (lane >> 3);
            int lc = (lane & 7) ^ (r & 7);
            gload_lds16((const char*)(Bb + (long)r * K + kt) + lc * 16,
                        (char*)&Bs[bf][0] + (wave * (GN / 4) + it * 8) * 128);
        }
    };

    constexpr int NLOADS = 4 + GN / 32;
    const int nk = K >> 6;
    stage(0, 0);
    int buf = 0;
#pragma unroll 1
    for (int ki = 0; ki < nk; ++ki) {
        if (ki + 1 < nk) {
            stage(buf ^ 1, (ki + 1) << 6);
            if (NLOADS == 8)
                asm volatile("s_waitcnt vmcnt(8)" ::: "memory");
            else
                asm volatile("s_waitcnt vmcnt(6)" ::: "memory");
        } else {
            asm volatile("s_waitcnt vmcnt(0)" ::: "memory");
        }
        BARRIER_ACQ;
#pragma unroll
        for (int kk = 0; kk < 2; ++kk) {
            h8 af[4], bf4[NFRAG];
#pragma unroll
            for (int m = 0; m < 4; ++m) {
                int row = wr * 64 + m * 16 + (lane & 15);
                int pc = (kk * 4 + (lane >> 4)) ^ (row & 7);
                af[m] = *(const h8*)(&As[buf][row * 64 + pc * 8]);
            }
#pragma unroll
            for (int n = 0; n < NFRAG; ++n) {
                int row = wc * (GN / 2) + n * 16 + (lane & 15);
                int pc = (kk * 4 + (lane >> 4)) ^ (row & 7);
                bf4[n] = *(const h8*)(&Bs[buf][row * 64 + pc * 8]);
            }
#pragma unroll
            for (int m = 0; m < 4; ++m)
#pragma unroll
                for (int n = 0; n < NFRAG; ++n)
                    acc[m][n] = __builtin_amdgcn_mfma_f32_16x16x32_f16(
                        af[m], bf4[n], acc[m][n], 0, 0, 0);
        }
        BARRIER_REL;
        buf ^= 1;
    }

#pragma unroll
    for (int n = 0; n < NFRAG; ++n) {
        int col = ntile * GN + wc * (GN / 2) + n * 16 + (lane & 15);
        const float* bp = (col < 1024) ? g.bias[seg][0]
                        : (col < 2048) ? g.bias[seg][1] : g.bias[seg][2];
        float bv = bp[col & 1023];
#pragma unroll
        for (int m = 0; m < 4; ++m) {
            int lrow = wr * 64 + m * 16 + ((lane >> 4) << 2);
#pragma unroll
            for (int r = 0; r < 4; ++r) {
                float v = acc[m][n][r] + bv;
                long off = crow0 + (long)(lrow + r) * N + col;
                if (OUT_F32) ((float*)g.C[seg])[off] = v;
                else         ((_Float16*)g.C[seg])[off] = (_Float16)v;
            }
        }
    }
}

// ---------------------------------------------------------------------------
// Kernel 3: FUSED pass2 (RMSNorm+RoPE Q/K, blocks 0..1151) + V-transpose
//   (blocks 1152..1727).
// ---------------------------------------------------------------------------
__device__ __forceinline__ float ssum8(h8 v) {
    float s = 0.f;
#pragma unroll
    for (int j = 0; j < 8; ++j) { float f = (float)v[j]; s += f * f; }
    return s;
}
__device__ __forceinline__ float red8(float s) {
    s += __shfl_xor(s, 1); s += __shfl_xor(s, 2); s += __shfl_xor(s, 4);
    return s;
}
__device__ __forceinline__ h8 norm_rope(h8 v, float rs_, const float* g, float gmul,
                                        const float* cs, const float* sn, int vis) {
    float f[8];
#pragma unroll
    for (int j = 0; j < 8; ++j) f[j] = (float)v[j] * rs_ * g[j] * gmul;
    h8 o;
    if (vis) {
#pragma unroll
        for (int j = 0; j < 8; j += 2) {
            float a = f[j], b = f[j + 1];
            o[j]     = (_Float16)(a * cs[j]     - b * sn[j]);
            o[j + 1] = (_Float16)(b * cs[j + 1] + a * sn[j + 1]);
        }
    } else {
#pragma unroll
        for (int j = 0; j < 8; ++j) o[j] = (_Float16)f[j];
    }
    return o;
}

__global__ __launch_bounds__(256)
void pass2_kernel(const _Float16* __restrict__ Yv, const _Float16* __restrict__ Yt,
                  const float* __restrict__ gqv, const float* __restrict__ gkv_,
                  const float* __restrict__ gqt, const float* __restrict__ gkt,
                  const float* __restrict__ rc, const float* __restrict__ rs,
                  _Float16* __restrict__ Q, _Float16* __restrict__ Kd,
                  _Float16* __restrict__ Vt)
{
    __shared__ _Float16 T[64 * 136];
    if (blockIdx.x >= 1152) {
        const int blk = blockIdx.x - 1152;   // bh*18 + ntile
        const int bh = blk / 18, ntl = blk - bh * 18;
        const int b = bh >> 4, h = bh & 15;
        const int npos0 = ntl * 128;
        const _Float16* Y; long m0;
        if (ntl >= 2) { Y = Yv; m0 = (long)b * 2048 + (npos0 - 256); }
        else          { Y = Yt; m0 = (long)b * 256 + npos0; }
        const int t = threadIdx.x;
        const _Float16* src = Y + m0 * 3072 + 2048 + h * 64;
#pragma unroll
        for (int ri = 0; ri < 4; ++ri) {
            int row = ri * 32 + (t >> 3);
            int c8 = t & 7;
            h8 v = *(const h8*)(src + (long)row * 3072 + c8 * 8);
#pragma unroll
            for (int j = 0; j < 8; ++j)
                T[(c8 * 8 + j) * 136 + row] = v[j];
        }
        __syncthreads();
        const int d = t >> 2, ch = t & 3;
        _Float16* dst = Vt + ((long)bh * 64 + d) * 2304 + npos0 + ch * 32;
#pragma unroll
        for (int k = 0; k < 4; ++k)
            *(h8*)(dst + k * 8) = *(const h8*)(&T[d * 136 + ch * 32 + k * 8]);
        return;
    }
    const int wave = threadIdx.x >> 6;
    const int lane = threadIdx.x & 63;
    const int row = blockIdx.x * 4 + wave;
    const int is_vis = row < 4096;
    const _Float16* y;
    const float *gq, *gk;
    int b, n, npos;
    if (is_vis) {
        y = Yv + (long)row * 3072; gq = gqv; gk = gkv_;
        b = row >> 11; n = row & 2047; npos = 256 + n;
    } else {
        int r2 = row - 4096;
        y = Yt + (long)r2 * 3072; gq = gqt; gk = gkt;
        b = r2 >> 8; n = r2 & 255; npos = n;
    }
    const int h0 = lane >> 3;
    const int d0 = (lane & 7) * 8;

    h8 q0 = *(const h8*)(y + lane * 8);
    h8 q1 = *(const h8*)(y + 512 + lane * 8);
    h8 k0 = *(const h8*)(y + 1024 + lane * 8);
    h8 k1 = *(const h8*)(y + 1536 + lane * 8);

    float ga[8], gb[8];
    *(float4*)(ga)     = *(const float4*)(gq + d0);
    *(float4*)(ga + 4) = *(const float4*)(gq + d0 + 4);
    *(float4*)(gb)     = *(const float4*)(gk + d0);
    *(float4*)(gb + 4) = *(const float4*)(gk + d0 + 4);
    float cs[8], sn[8];
    if (is_vis) {
        *(float4*)(cs)     = *(const float4*)(rc + n * 64 + d0);
        *(float4*)(cs + 4) = *(const float4*)(rc + n * 64 + d0 + 4);
        *(float4*)(sn)     = *(const float4*)(rs + n * 64 + d0);
        *(float4*)(sn + 4) = *(const float4*)(rs + n * 64 + d0 + 4);
    }

    const float rq0 = rsqrtf(red8(ssum8(q0)) * (1.0f / 64.0f) + 1e-6f);
    const float rq1 = rsqrtf(red8(ssum8(q1)) * (1.0f / 64.0f) + 1e-6f);
    const float rk0 = rsqrtf(red8(ssum8(k0)) * (1.0f / 64.0f) + 1e-6f);
    const float rk1 = rsqrtf(red8(ssum8(k1)) * (1.0f / 64.0f) + 1e-6f);

    const float qmul = 0.125f * LOG2E;
    const long obA = (((long)b * 16 + h0)      * 2304 + npos) * 64 + d0;
    const long obB = (((long)b * 16 + h0 + 8)  * 2304 + npos) * 64 + d0;
    *(h8*)(Q + obA)  = norm_rope(q0, rq0, ga, qmul, cs, sn, is_vis);
    *(h8*)(Q + obB)  = norm_rope(q1, rq1, ga, qmul, cs, sn, is_vis);
    *(h8*)(Kd + obA) = norm_rope(k0, rk0, gb, 1.0f, cs, sn, is_vis);
    *(h8*)(Kd + obB) = norm_rope(k1, rk1, gb, 1.0f, cs, sn, is_vis);
}

// ---------------------------------------------------------------------------
// Kernel 4: flash attention — R13-proven body (256 thr, QBLK=128, KVBLK=64
//   double-buffered, stage->vmcnt(4)->barrier->compute->barrier, split psum).
//   launch_bounds(256,4). Split-K ns in {2,4}.
// ---------------------------------------------------------------------------
__device__ __forceinline__ void attn_stage(const char* Kt, const char* Vt, char* S,
                                           int bufB, int t,
                                           int gK0, int gK1, int gV0, int gV1,
                                           int ldsW) {
    const char* kt = Kt + (long)t * 8192;
    const char* vt = Vt + (long)t * 128;
    gload_lds16(kt + gK0, S + bufB + ldsW);
    gload_lds16(kt + gK1, S + bufB + 4096 + ldsW);
    gload_lds16(vt + gV0, S + 16384 + bufB + ldsW);
    gload_lds16(vt + gV1, S + 16384 + bufB + 4096 + ldsW);
}

__device__ __forceinline__ void pv_half(const float* p, const char* S, int vbase,
                                        const int* off, int kblk,
                                        f16x16* oacc, float& psum) {
    const h2 one2 = {(_Float16)1.f, (_Float16)1.f};
    float a0 = 0.f, a1 = 0.f;
#pragma unroll
    for (int kb = 0; kb < 2; ++kb) {
        unsigned w0 = __builtin_bit_cast(unsigned,
            __builtin_amdgcn_cvt_pkrtz(p[8 * kb + 0], p[8 * kb + 1]));
        unsigned w1 = __builtin_bit_cast(unsigned,
            __builtin_amdgcn_cvt_pkrtz(p[8 * kb + 2], p[8 * kb + 3]));
        unsigned w2 = __builtin_bit_cast(unsigned,
            __builtin_amdgcn_cvt_pkrtz(p[8 * kb + 4], p[8 * kb + 5]));
        unsigned w3 = __builtin_bit_cast(unsigned,
            __builtin_amdgcn_cvt_pkrtz(p[8 * kb + 6], p[8 * kb + 7]));
        a0 = __builtin_amdgcn_fdot2(__builtin_bit_cast(h2, w0), one2, a0, false);
        a1 = __builtin_amdgcn_fdot2(__builtin_bit_cast(h2, w1), one2, a1, false);
        a0 = __builtin_amdgcn_fdot2(__builtin_bit_cast(h2, w2), one2, a0, false);
        a1 = __builtin_amdgcn_fdot2(__builtin_bit_cast(h2, w3), one2, a1, false);
        asm("v_permlane32_swap_b32 %0, %1" : "+v"(w0), "+v"(w2));
        asm("v_permlane32_swap_b32 %0, %1" : "+v"(w1), "+v"(w3));
        union { unsigned u[4]; h8 v; } pa;
        pa.u[0] = w0; pa.u[1] = w1; pa.u[2] = w2; pa.u[3] = w3;
#pragma unroll
        for (int dblk = 0; dblk < 2; ++dblk) {
            h8 vb = *(const h8*)(S + vbase + dblk * 4096 + off[kblk * 2 + kb]);
            oacc[dblk] = __builtin_amdgcn_mfma_f32_32x32x16_f16(
                pa.v, vb, oacc[dblk], 0, 0, 0);
        }
    }
    psum += a0 + a1;
}

__device__ __forceinline__ void attn_tile(const char* S, int bufB, const int* off,
                                          const h8* qf, f16x16* oacc, float& psum) {
    const f16x16 kZero = {};
    f16x16 st0, st1;
    {
        h8 ka0 = *(const h8*)(S + bufB + off[0]);
        h8 ka1 = *(const h8*)(S + bufB + 4096 + off[0]);
        st0 = __builtin_amdgcn_mfma_f32_32x32x16_f16(ka0, qf[0], kZero, 0, 0, 0);
        st1 = __builtin_amdgcn_mfma_f32_32x32x16_f16(ka1, qf[0], kZero, 0, 0, 0);
    }
#pragma unroll
    for (int ds = 1; ds < 4; ++ds) {
        h8 ka0 = *(const h8*)(S + bufB + off[ds]);
        h8 ka1 = *(const h8*)(S + bufB + 4096 + off[ds]);
        st0 = __builtin_amdgcn_mfma_f32_32x32x16_f16(ka0, qf[ds], st0, 0, 0, 0);
        st1 = __builtin_amdgcn_mfma_f32_32x32x16_f16(ka1, qf[ds], st1, 0, 0, 0);
    }
    float p0[16], p1[16];
#pragma unroll
    for (int r = 0; r < 16; ++r) { p0[r] = exp2f(st0[r]); p1[r] = exp2f(st1[r]); }
    pv_half(p0, S, 16384 + bufB, off, 0, oacc, psum);
    pv_half(p1, S, 16384 + bufB, off, 1, oacc, psum);
}

__global__ __launch_bounds__(256, 4)
void attn_kernel(const _Float16* __restrict__ Qg,
                 const _Float16* __restrict__ Kg,
                 const _Float16* __restrict__ Vg,   // [bh][64][2304]
                 _Float16* __restrict__ Op,         // [ns][b][2304][1024]
                 float* __restrict__ Lp,            // [ns][bh][2304]
                 int nt, int cpx)
{
    __shared__ __align__(16) char S[32768];
    const int lane = threadIdx.x & 63;
    const int wave = threadIdx.x >> 6;
    const int l31 = lane & 31, hi = lane >> 5;
    const int d0 = blockIdx.x;
    const int id = (d0 & 7) * cpx + (d0 >> 3);
    const int split = id / 576;
    const int rem = id - split * 576;
    const int bh = rem / 18;
    const int qb = rem - bh * 18;
    const int b = bh >> 4, h = bh & 15;
    const _Float16* Qbh = Qg + (long)bh * 2304 * 64;
    const char* Kt = (const char*)(Kg + (long)bh * 2304 * 64) + (long)split * nt * 8192;
    const char* Vt = (const char*)(Vg + (long)bh * 64 * 2304) + (long)split * nt * 128;
    _Float16* Ops = Op + (long)split * 4718592;
    float* Lps = Lp + (long)split * 73728;
    const int q0 = qb * 128 + wave * 32;

    h8 qf[4];
#pragma unroll
    for (int ds = 0; ds < 4; ++ds)
        qf[ds] = *(const h8*)(Qbh + (long)(q0 + l31) * 64 + ds * 16 + hi * 8);

    const int sg16 = ((lane & 7) ^ (lane >> 3)) * 16;
    const int rK = wave * 8 + (lane >> 3);
    const int gK0 = rK * 128 + sg16;
    const int gK1 = gK0 + 32 * 128;
    const int gV0 = rK * 4608 + sg16;
    const int gV1 = gV0 + 32 * 4608;
    const int ldsW = wave * 1024;
    int off[4];
#pragma unroll
    for (int j = 0; j < 4; ++j)
        off[j] = l31 * 128 + (((j * 2 + hi) ^ (l31 & 7)) * 16);

    f16x16 oacc[2] = {};
    float psum = 0.f;

    attn_stage(Kt, Vt, S, 0, 0, gK0, gK1, gV0, gV1, ldsW);
    int buf = 0;
#pragma unroll 1
    for (int t = 0; t < nt; ++t) {
        if (t + 1 < nt) {
            attn_stage(Kt, Vt, S, (buf ^ 1) * 8192, t + 1, gK0, gK1, gV0, gV1, ldsW);
            asm volatile("s_waitcnt vmcnt(4)" ::: "memory");
        } else {
            asm volatile("s_waitcnt vmcnt(0)" ::: "memory");
        }
        BARRIER_ACQ;
        __builtin_amdgcn_s_setprio(1);
        attn_tile(S, buf * 8192, off, qf, oacc, psum);
        __builtin_amdgcn_s_setprio(0);
        BARRIER_REL;
        buf ^= 1;
    }

    float lsum = psum + __shfl_xor(psum, 32);
    if (hi == 0) Lps[(long)bh * 2304 + q0 + l31] = lsum;
#pragma unroll
    for (int dblk = 0; dblk < 2; ++dblk) {
        int dcol = h * 64 + dblk * 32 + l31;
#pragma unroll
        for (int r = 0; r < 16; ++r) {
            int qrow = q0 + (r & 3) + 8 * (r >> 2) + 4 * hi;
            Ops[((long)b * 2304 + qrow) * 1024 + dcol] = (_Float16)oacc[dblk][r];
        }
    }
}

// ---------------------------------------------------------------------------
// Kernel 5: combine ns KV-splits: O = sum(O_s) / sum(l_s).
// ---------------------------------------------------------------------------
__global__ __launch_bounds__(256)
void combine_kernel(const _Float16* __restrict__ Op,
                    const float* __restrict__ Lp,
                    _Float16* __restrict__ Oh, int ns)
{
    long i = ((long)blockIdx.x * 256 + threadIdx.x) * 8;
    long row = i >> 10;
    int bb = row >= 2304;
    int n = (int)row - bb * 2304;
    int h = ((int)i & 1023) >> 6;
    long lidx = ((long)(bb * 16 + h)) * 2304 + n;
    float l = 0.f;
    float acc[8] = {};
    for (int s = 0; s < ns; ++s) {
        l += Lp[(long)s * 73728 + lidx];
        h8 a = *(const h8*)(Op + (long)s * 4718592 + i);
#pragma unroll
        for (int j = 0; j < 8; ++j) acc[j] += (float)a[j];
    }
    float inv = 1.0f / l;
    h8 o;
#pragma unroll
    for (int j = 0; j < 8; ++j) o[j] = (_Float16)(acc[j] * inv);
    *(h8*)(Oh + i) = o;
}

// ---------------------------------------------------------------------------
extern "C" void kernel_launch(void* const* d_in, const int* in_sizes, int n_in,
                              void* d_out, int out_size, void* d_ws, size_t ws_size,
                              hipStream_t stream)
{
    const float* vis_x    = (const float*)d_in[0];
    const float* txt_x    = (const float*)d_in[1];
    const float* rope_cos = (const float*)d_in[2];
    const float* rope_sin = (const float*)d_in[3];
    const float* vis_qw = (const float*)d_in[4];
    const float* vis_qb = (const float*)d_in[5];
    const float* vis_kw = (const float*)d_in[6];
    const float* vis_kb = (const float*)d_in[7];
    const float* vis_vw = (const float*)d_in[8];
    const float* vis_vb = (const float*)d_in[9];
    const float* vis_ow = (const float*)d_in[10];
    const float* vis_ob = (const float*)d_in[11];
    const float* txt_qw = (const float*)d_in[12];
    const float* txt_qb = (const float*)d_in[13];
    const float* txt_kw = (const float*)d_in[14];
    const float* txt_kb = (const float*)d_in[15];
    const float* txt_vw = (const float*)d_in[16];
    const float* txt_vb = (const float*)d_in[17];
    const float* txt_ow = (const float*)d_in[18];
    const float* txt_ob = (const float*)d_in[19];
    const float* vis_qn = (const float*)d_in[20];
    const float* vis_kn = (const float*)d_in[21];
    const float* txt_qn = (const float*)d_in[22];
    const float* txt_kn = (const float*)d_in[23];

    char* ws = (char*)d_ws;
    _Float16* Xvis  = (_Float16*)(ws);
    _Float16* Xtxt  = (_Float16*)(ws + 8388608);
    _Float16* Qh    = (_Float16*)(ws);              // aliases X (dead after QKV gemm)
    _Float16* WqkvV = (_Float16*)(ws + 9437184);
    _Float16* WqkvT = (_Float16*)(ws + 15728640);
    _Float16* WoV   = (_Float16*)(ws + 22020096);
    _Float16* WoT   = (_Float16*)(ws + 24117248);
    _Float16* Yvis  = (_Float16*)(ws + 26214400);   // dead after pass2
    _Float16* Ytxt  = (_Float16*)(ws + 51380224);   // dead after pass2
    _Float16* Kh    = (_Float16*)(ws + 54525952);
    _Float16* Vth   = (_Float16*)(ws + 63963136);

    const int ns = (ws_size >= 112328704) ? 4 : 2;
    const int nt = (ns == 4) ? 9 : 18;              // KV tiles of 64 per split
    _Float16* OpP;
    if (ns == 4) OpP = (_Float16*)(ws + 73400320);
    else         OpP = (_Float16*)(ws + 26214400);
    float* LpP = (float*)((char*)OpP + (size_t)ns * 9437184);
    _Float16* Oh = OpP;   // combine output aliases partial 0 (read-before-write)

    CastArgs ca;
    ca.src[0] = vis_x;  ca.dst[0] = Xvis;
    ca.src[1] = txt_x;  ca.dst[1] = Xtxt;
    ca.src[2] = vis_qw; ca.dst[2] = WqkvV;
    ca.src[3] = vis_kw; ca.dst[3] = WqkvV + 1048576;
    ca.src[4] = vis_vw; ca.dst[4] = WqkvV + 2097152;
    ca.src[5] = txt_qw; ca.dst[5] = WqkvT;
    ca.src[6] = txt_kw; ca.dst[6] = WqkvT + 1048576;
    ca.src[7] = txt_vw; ca.dst[7] = WqkvT + 2097152;
    ca.src[8] = vis_ow; ca.dst[8] = WoV;
    ca.src[9] = txt_ow; ca.dst[9] = WoT;
    cast_all_kernel<<<12800, 256, 0, stream>>>(ca);

    GemmDesc gq;
    gq.A[0] = Xvis;  gq.A[1] = Xtxt;
    gq.W[0] = WqkvV; gq.W[1] = WqkvT;
    gq.C[0] = (char*)Yvis; gq.C[1] = (char*)Ytxt;
    gq.bias[0][0] = vis_qb; gq.bias[0][1] = vis_kb; gq.bias[0][2] = vis_vb;
    gq.bias[1][0] = txt_qb; gq.bias[1][1] = txt_kb; gq.bias[1][2] = txt_vb;
    gq.bsA[0] = 0; gq.bsA[1] = 0;
    gq.aoff[0] = 0; gq.aoff[1] = 0;
    gq.bsC[0] = 0; gq.bsC[1] = 0;
    gq.mshift[0] = 5; gq.mshift[1] = 5;
    gq.mcut = 32;
    gemm_kernel<false, 128><<<864, 256, 0, stream>>>(gq, 1024, 3072, 9, 12, 2);

    pass2_kernel<<<1728, 256, 0, stream>>>(
        Yvis, Ytxt, vis_qn, vis_kn, txt_qn, txt_kn, rope_cos, rope_sin,
        Qh, Kh, Vth);

    attn_kernel<<<576 * ns, 256, 0, stream>>>(Qh, Kh, Vth, OpP, LpP, nt, 72 * ns);
    combine_kernel<<<2304, 256, 0, stream>>>(OpP, LpP, Oh, ns);

    GemmDesc go;
    go.A[0] = Oh; go.A[1] = Oh;
    go.W[0] = WoV; go.W[1] = WoT;
    go.C[0] = (char*)d_out; go.C[1] = (char*)((float*)d_out + 4194304);
    go.bias[0][0] = vis_ob; go.bias[0][1] = vis_ob; go.bias[0][2] = vis_ob;
    go.bias[1][0] = txt_ob; go.bias[1][1] = txt_ob; go.bias[1][2] = txt_ob;
    go.bsA[0] = 2359296;  go.bsA[1] = 2359296;
    go.aoff[0] = 262144;  go.aoff[1] = 0;
    go.bsC[0] = 2097152;  go.bsC[1] = 262144;
    go.mshift[0] = 4; go.mshift[1] = 1;
    go.mcut = 32;
    gemm_kernel<true, 64><<<576, 256, 0, stream>>>(go, 1024, 1024, 9, 8, 2);
}